// Round 15
// baseline (344.088 us; speedup 1.0000x reference)
//
#include <hip/hip_runtime.h>
#include <hip/hip_bf16.h>
#include <hip/hip_cooperative_groups.h>

namespace cg = cooperative_groups;

#define NN 20000
#define NE 320000
#define DD 256

typedef __attribute__((ext_vector_type(8))) short bf16x8;   // 8 bf16 = 4 VGPR (MFMA A/B frag)
typedef __attribute__((ext_vector_type(4))) float f32x4;    // MFMA C/D frag
typedef __attribute__((ext_vector_type(4))) int   int4v;    // 16B chunk
typedef __attribute__((ext_vector_type(4))) float float4v;

typedef __attribute__((address_space(1))) unsigned int gas_uint;
typedef __attribute__((address_space(3))) unsigned int las_uint;
static __device__ __forceinline__ void gload16(const void* g, void* l) {
    __builtin_amdgcn_global_load_lds((gas_uint*)g, (las_uint*)l, 16, 0, 0);
}

__device__ __forceinline__ unsigned short f2bf(float f) {
    union { float f; unsigned u; } v; v.f = f;
    unsigned r = v.u + 0x7fffu + ((v.u >> 16) & 1u);   // RNE
    return (unsigned short)(r >> 16);
}
__device__ __forceinline__ float bf2f(unsigned short h) {
    union { unsigned u; float f; } v; v.u = ((unsigned)h) << 16;
    return v.f;
}
__device__ __forceinline__ float fast_sigmoid(float x) {
    return 1.f / (1.f + __expf(-x));                   // inf-safe: 1/(1+inf)=0
}
__device__ __forceinline__ float fast_tanh(float x) {
    x = fminf(fmaxf(x, -30.f), 30.f);                  // clamp: avoid inf/inf NaN
    float e = __expf(-2.f * x);
    return (1.f - e) / (1.f + e);
}

// ---------------- fused prologue: casts + Wc5 h-half + hist, one dispatch (R13) ----------------
__global__ void prep_kernel(const float* __restrict__ x, unsigned short* __restrict__ hbfA,
                            const float* __restrict__ W, unsigned short* __restrict__ wnb,
                            const float* __restrict__ wih, unsigned short* __restrict__ wihb,
                            const float* __restrict__ whh, unsigned short* __restrict__ wc5,
                            const int* __restrict__ edst, int* __restrict__ deg) {
    const int b = blockIdx.x, t = threadIdx.x;
    if (b < 5000) {
        int i = (b * 256 + t) * 4;
        float4v v = *reinterpret_cast<const float4v*>(x + i);
        uint2 o;
        o.x = (unsigned)f2bf(v.x) | ((unsigned)f2bf(v.y) << 16);
        o.y = (unsigned)f2bf(v.z) | ((unsigned)f2bf(v.w) << 16);
        *reinterpret_cast<uint2*>(hbfA + i) = o;
    } else if (b < 5320) {
        int i = ((b - 5000) * 256 + t) * 4;
        float4v v = *reinterpret_cast<const float4v*>(W + i);
        uint2 o;
        o.x = (unsigned)f2bf(v.x) | ((unsigned)f2bf(v.y) << 16);
        o.y = (unsigned)f2bf(v.z) | ((unsigned)f2bf(v.w) << 16);
        *reinterpret_cast<uint2*>(wnb + i) = o;
    } else if (b < 5512) {
        int i = ((b - 5320) * 256 + t) * 4;
        float4v v = *reinterpret_cast<const float4v*>(wih + i);
        uint2 o;
        o.x = (unsigned)f2bf(v.x) | ((unsigned)f2bf(v.y) << 16);
        o.y = (unsigned)f2bf(v.z) | ((unsigned)f2bf(v.w) << 16);
        *reinterpret_cast<uint2*>(wihb + i) = o;
    } else if (b < 5704) {
        int id = (b - 5512) * 256 + t;                // 768 n3 x 64 k-chunks
        int n3 = id >> 6, k0 = (id & 63) * 4;
        int g3 = (n3 >> 4) % 3;
        int d = (n3 / 48) * 16 + (n3 & 15);
        int gr = g3 * 256 + d;                        // g3: 0=r, 1=z, 2=h_n
        float4v v = *reinterpret_cast<const float4v*>(whh + gr * 256 + k0);
        uint2 o;
        o.x = (unsigned)f2bf(v.x) | ((unsigned)f2bf(v.y) << 16);
        o.y = (unsigned)f2bf(v.z) | ((unsigned)f2bf(v.w) << 16);
#pragma unroll
        for (int l = 0; l < 5; ++l)
            *reinterpret_cast<uint2*>(wc5 + ((size_t)(l * 2 + 1) * 768 + n3) * 256 + k0) = o;
    } else {
        int e = (b - 5704) * 256 + t;
        if (e < NE) atomicAdd(&deg[edst[e]], 1);
    }
}

// P = W_all @ Wih^T, epilogue writes DIRECTLY into wc5 agg-half (hf=0) positions. (R13)
__global__ __launch_bounds__(256) void pgemm_kernel(const unsigned short* __restrict__ A,
                                                    const unsigned short* __restrict__ Bt,
                                                    unsigned short* __restrict__ wc5) {
    __shared__ __align__(16) unsigned short As[128 * 64];
    __shared__ __align__(16) unsigned short Bs[64 * 64];
    const int t = threadIdx.x;
    const int lane = t & 63;
    const int w = t >> 6;
    const int wr = w >> 1, wc = w & 1;
    const int m0 = blockIdx.y * 128;
    const int n0 = blockIdx.x * 64;

    f32x4 acc[4][2];
    const f32x4 z4 = {0.f, 0.f, 0.f, 0.f};
    for (int i = 0; i < 4; ++i) for (int j = 0; j < 2; ++j) acc[i][j] = z4;

    for (int kt = 0; kt < 4; ++kt) {
        const int k0 = kt * 64;
#pragma unroll
        for (int rnd = 0; rnd < 4; ++rnd) {
            int cb = rnd * 256 + (w << 6);
            int c = cb + lane;
            int row = c >> 3, sl = c & 7;
            int gsl = sl ^ (row & 7);
            gload16(A + (size_t)(m0 + row) * 256 + k0 + gsl * 8, &As[cb * 8]);
        }
#pragma unroll
        for (int rnd = 0; rnd < 2; ++rnd) {
            int cb = rnd * 256 + (w << 6);
            int c = cb + lane;
            int row = c >> 3, sl = c & 7;
            int gsl = sl ^ (row & 7);
            gload16(Bt + (size_t)(n0 + row) * 256 + k0 + gsl * 8, &Bs[cb * 8]);
        }
        __syncthreads();
#pragma unroll
        for (int ks = 0; ks < 2; ++ks) {
            const int slot = ks * 4 + (lane >> 4);
            bf16x8 a[4], b[2];
#pragma unroll
            for (int mi = 0; mi < 4; ++mi) {
                int row = wr * 64 + mi * 16 + (lane & 15);
                a[mi] = *reinterpret_cast<const bf16x8*>(&As[row * 64 + ((slot ^ (row & 7)) << 3)]);
            }
#pragma unroll
            for (int ni = 0; ni < 2; ++ni) {
                int row = wc * 32 + ni * 16 + (lane & 15);
                b[ni] = *reinterpret_cast<const bf16x8*>(&Bs[row * 64 + ((slot ^ (row & 7)) << 3)]);
            }
#pragma unroll
            for (int mi = 0; mi < 4; ++mi)
#pragma unroll
                for (int ni = 0; ni < 2; ++ni)
                    acc[mi][ni] = __builtin_amdgcn_mfma_f32_16x16x32_bf16(a[mi], b[ni], acc[mi][ni], 0, 0, 0);
        }
        __syncthreads();
    }
#pragma unroll
    for (int mi = 0; mi < 4; ++mi)
#pragma unroll
        for (int ni = 0; ni < 2; ++ni)
#pragma unroll
            for (int r = 0; r < 4; ++r) {
                int grow = m0 + wr * 64 + mi * 16 + (lane >> 4) * 4 + r;   // = l*256 + k
                int gcol = n0 + wc * 32 + ni * 16 + (lane & 15);           // = gate_row
                int l = grow >> 8, k = grow & 255;
                int g3 = gcol >> 8, d = gcol & 255;                        // g3: 0=r,1=z,2=i_n
                int n3 = (d >> 4) * 48 + g3 * 16 + (d & 15);
                wc5[((size_t)(l * 2) * 768 + n3) * 256 + k] = f2bf(acc[mi][ni][r]);
            }
}

// ---------------- CSR build ----------------

__global__ __launch_bounds__(1024) void scan_kernel(const int* __restrict__ deg, int* __restrict__ base) {
    __shared__ int part[1024];
    const int t = threadIdx.x;
    const int CH = 20;
    int start = t * CH;
    int s = 0;
    for (int i = 0; i < CH; ++i) { int idx = start + i; if (idx < NN) s += deg[idx]; }
    part[t] = s; __syncthreads();
    for (int off = 1; off < 1024; off <<= 1) {
        int v = (t >= off) ? part[t - off] : 0;
        __syncthreads();
        part[t] += v;
        __syncthreads();
    }
    int run = (t == 0) ? 0 : part[t - 1];
    for (int i = 0; i < CH; ++i) {
        int idx = start + i;
        if (idx < NN) { base[idx] = run; run += deg[idx]; }
    }
    if (t == 1023) base[NN] = run;
}

// fill destroys basep: afterward basep[n] = END offset of node n (start = end - deg[n]).
__global__ void fill_kernel(const int* __restrict__ src, const int* __restrict__ dst,
                            const float* __restrict__ attr, int* __restrict__ base,
                            int* __restrict__ ssrc, float* __restrict__ sattr) {
    int e = blockIdx.x * 256 + threadIdx.x;
    if (e >= NE) return;
    int d = dst[e];
    int pos = atomicAdd(&base[d], 1);
    ssrc[pos] = src[e];
    sattr[pos] = attr[e];
}

// ---------------- standalone gather (fallback path; end-offset CSR) ----------
__global__ __launch_bounds__(256) void gather_agg_kernel(const unsigned short* __restrict__ Hbf,
                                                         const int* __restrict__ basee,
                                                         const int* __restrict__ deg,
                                                         const int* __restrict__ ssrc,
                                                         const float* __restrict__ sattr,
                                                         unsigned short* __restrict__ AggBf) {
    int node = blockIdx.x * 4 + (threadIdx.x >> 6);
    if (node >= NN) return;
    int lane = threadIdx.x & 63;
    int q = lane >> 4;
    int ql = lane & 15;
    int b1 = basee[node];
    int b0 = b1 - deg[node];
    float ac[16];
#pragma unroll
    for (int j = 0; j < 16; ++j) ac[j] = 0.f;
    for (int p = b0 + q; p < b1; p += 4) {
        int s = ssrc[p];
        float a = sattr[p];
        const unsigned short* rowp = Hbf + (size_t)s * 256 + ql * 16;
        int4v v0 = *reinterpret_cast<const int4v*>(rowp);
        int4v v1 = *reinterpret_cast<const int4v*>(rowp + 8);
#pragma unroll
        for (int j = 0; j < 4; ++j) {
            unsigned u0 = (unsigned)v0[j];
            ac[2 * j]     += a * bf2f((unsigned short)(u0 & 0xffff));
            ac[2 * j + 1] += a * bf2f((unsigned short)(u0 >> 16));
            unsigned u1 = (unsigned)v1[j];
            ac[8 + 2 * j]     += a * bf2f((unsigned short)(u1 & 0xffff));
            ac[8 + 2 * j + 1] += a * bf2f((unsigned short)(u1 >> 16));
        }
    }
#pragma unroll
    for (int j = 0; j < 16; ++j) {
        ac[j] += __shfl_xor(ac[j], 16);
        ac[j] += __shfl_xor(ac[j], 32);
    }
    if (q == 0) {
        unsigned ou[8];
#pragma unroll
        for (int j = 0; j < 8; ++j)
            ou[j] = (unsigned)f2bf(ac[2 * j]) | ((unsigned)f2bf(ac[2 * j + 1]) << 16);
        unsigned short* op = AggBf + (size_t)node * 256 + ql * 16;
        *reinterpret_cast<int4v*>(op)     = *reinterpret_cast<int4v*>(&ou[0]);
        *reinterpret_cast<int4v*>(op + 8) = *reinterpret_cast<int4v*>(&ou[4]);
    }
}

// ---------------- standalone gru (fallback path; R13's gru4 verbatim) ----------
__global__ __launch_bounds__(512) void gru4_kernel(const unsigned short* __restrict__ Abf,
                                                   const unsigned short* __restrict__ Hbf,
                                                   const unsigned short* __restrict__ Wc,
                                                   const float* __restrict__ b_ih,
                                                   const float* __restrict__ b_hh,
                                                   const float* __restrict__ x_f32,
                                                   float* __restrict__ h_out,
                                                   unsigned short* __restrict__ Hbf_out,
                                                   int first, int last) {
    __shared__ __align__(16) unsigned short As[128 * 64];
    __shared__ __align__(16) unsigned short Bs[96 * 64];
    const int t = threadIdx.x;
    const int lane = t & 63;
    const int w = t >> 6;
    const int wm = w >> 1, wn = w & 1;
    int b = blockIdx.x;
    int ww = (b & 7) * 158 + (b >> 3);                 // XCD-chunked (1264 = 8*158)
    const int mt = ww >> 3, dgp = ww & 7;
    const int m0 = mt * 128;

    f32x4 aR[2], aZ[2], aI[2], aH[2];
    const f32x4 z4 = {0.f, 0.f, 0.f, 0.f};
#pragma unroll
    for (int i = 0; i < 2; ++i) { aR[i] = z4; aZ[i] = z4; aI[i] = z4; aH[i] = z4; }

    auto do_half = [&](const unsigned short* __restrict__ aptr,
                       const unsigned short* __restrict__ wcb,
                       f32x4 (&aX)[2]) {
        for (int kq = 0; kq < 4; ++kq) {
            const int ka = kq * 64;
#pragma unroll
            for (int rnd = 0; rnd < 2; ++rnd) {
                int cb = rnd * 512 + (w << 6);
                int c = cb + lane;
                int row = c >> 3, sl = c & 7;
                int gsl = sl ^ (row & 7);
                gload16(aptr + (size_t)(m0 + row) * 256 + ka + gsl * 8, &As[cb * 8]);
            }
            {
                int cb = (w << 6);
                int c = cb + lane;
                int row = c >> 3, sl = c & 7;
                int gsl = sl ^ (row & 7);
                gload16(wcb + (size_t)(dgp * 96 + row) * 256 + ka + gsl * 8, &Bs[cb * 8]);
            }
            if (w < 4) {
                int cb = 512 + (w << 6);
                int c = cb + lane;
                int row = c >> 3, sl = c & 7;
                int gsl = sl ^ (row & 7);
                gload16(wcb + (size_t)(dgp * 96 + row) * 256 + ka + gsl * 8, &Bs[cb * 8]);
            }
            __syncthreads();
#pragma unroll
            for (int ks = 0; ks < 2; ++ks) {
                const int slot = ks * 4 + (lane >> 4);
                bf16x8 a[2], bfr[3];
#pragma unroll
                for (int mi = 0; mi < 2; ++mi) {
                    int row = wm * 32 + mi * 16 + (lane & 15);
                    a[mi] = *reinterpret_cast<const bf16x8*>(&As[row * 64 + ((slot ^ (row & 7)) << 3)]);
                }
#pragma unroll
                for (int g3 = 0; g3 < 3; ++g3) {
                    int row = wn * 48 + g3 * 16 + (lane & 15);
                    bfr[g3] = *reinterpret_cast<const bf16x8*>(&Bs[row * 64 + ((slot ^ (row & 7)) << 3)]);
                }
#pragma unroll
                for (int mi = 0; mi < 2; ++mi) {
                    aR[mi] = __builtin_amdgcn_mfma_f32_16x16x32_bf16(a[mi], bfr[0], aR[mi], 0, 0, 0);
                    aZ[mi] = __builtin_amdgcn_mfma_f32_16x16x32_bf16(a[mi], bfr[1], aZ[mi], 0, 0, 0);
                    aX[mi] = __builtin_amdgcn_mfma_f32_16x16x32_bf16(a[mi], bfr[2], aX[mi], 0, 0, 0);
                }
            }
            __syncthreads();
        }
    };

    do_half(Abf, Wc, aI);
    do_half(Hbf, Wc + 768 * 256, aH);

    const int d = (dgp * 2 + wn) * 16 + (lane & 15);
    const float bir = b_ih[d],        bhr = b_hh[d];
    const float biz = b_ih[256 + d],  bhz = b_hh[256 + d];
    const float bin_ = b_ih[512 + d], bhn = b_hh[512 + d];
#pragma unroll
    for (int mi = 0; mi < 2; ++mi)
#pragma unroll
        for (int r = 0; r < 4; ++r) {
            int grow = m0 + wm * 32 + mi * 16 + (lane >> 4) * 4 + r;
            if (grow >= NN) continue;
            size_t idx = (size_t)grow * 256 + d;
            float rr = fast_sigmoid(aR[mi][r] + bir + bhr);
            float zz = fast_sigmoid(aZ[mi][r] + biz + bhz);
            float nn = fast_tanh(aI[mi][r] + bin_ + rr * (aH[mi][r] + bhn));
            float hp = first ? x_f32[idx] : bf2f(Hbf[idx]);
            float hv = (1.f - zz) * nn + zz * hp;
            if (last) h_out[idx] = hv;
            Hbf_out[idx] = f2bf(hv);
        }
}

// ---------------- persistent cooperative mega kernel (grid-stride; robust grid) -------
__global__ __launch_bounds__(512, 8) void mega_kernel(
        unsigned short* __restrict__ hbfA, unsigned short* __restrict__ hbfB,
        unsigned short* __restrict__ aggbf, const unsigned short* __restrict__ wc5,
        const int* __restrict__ basee, const int* __restrict__ deg,
        const int* __restrict__ ssrc, const float* __restrict__ sattr,
        const float* __restrict__ b_ih, const float* __restrict__ b_hh,
        const float* __restrict__ x_f32, float* __restrict__ h_out) {
    cg::grid_group grid = cg::this_grid();
    __shared__ __align__(16) unsigned short As[128 * 64];
    __shared__ __align__(16) unsigned short Bs[96 * 64];
    const int t = threadIdx.x;
    const int lane = t & 63;
    const int w = t >> 6;
    const int wm = w >> 1, wn = w & 1;
    const int bid = blockIdx.x;
    const int nblk = gridDim.x;

    for (int l = 0; l < 5; ++l) {
        const unsigned short* hcur = (l & 1) ? hbfB : hbfA;
        unsigned short* hnxt = (l & 1) ? hbfA : hbfB;
        const int first = (l == 0), last = (l == 4);

        // ---- gather: one wave per node, grid-stride ----
        for (int node = bid * 8 + w; node < NN; node += nblk * 8) {
            int q = lane >> 4;
            int ql = lane & 15;
            int b1 = basee[node];
            int b0 = b1 - deg[node];
            float ac[16];
#pragma unroll
            for (int j = 0; j < 16; ++j) ac[j] = 0.f;
            for (int p = b0 + q; p < b1; p += 4) {
                int s = ssrc[p];
                float a = sattr[p];
                const unsigned short* rowp = hcur + (size_t)s * 256 + ql * 16;
                int4v v0 = *reinterpret_cast<const int4v*>(rowp);
                int4v v1 = *reinterpret_cast<const int4v*>(rowp + 8);
#pragma unroll
                for (int j = 0; j < 4; ++j) {
                    unsigned u0 = (unsigned)v0[j];
                    ac[2 * j]     += a * bf2f((unsigned short)(u0 & 0xffff));
                    ac[2 * j + 1] += a * bf2f((unsigned short)(u0 >> 16));
                    unsigned u1 = (unsigned)v1[j];
                    ac[8 + 2 * j]     += a * bf2f((unsigned short)(u1 & 0xffff));
                    ac[8 + 2 * j + 1] += a * bf2f((unsigned short)(u1 >> 16));
                }
            }
#pragma unroll
            for (int j = 0; j < 16; ++j) {
                ac[j] += __shfl_xor(ac[j], 16);
                ac[j] += __shfl_xor(ac[j], 32);
            }
            if (q == 0) {
                unsigned ou[8];
#pragma unroll
                for (int j = 0; j < 8; ++j)
                    ou[j] = (unsigned)f2bf(ac[2 * j]) | ((unsigned)f2bf(ac[2 * j + 1]) << 16);
                unsigned short* op = aggbf + (size_t)node * 256 + ql * 16;
                *reinterpret_cast<int4v*>(op)     = *reinterpret_cast<int4v*>(&ou[0]);
                *reinterpret_cast<int4v*>(op + 8) = *reinterpret_cast<int4v*>(&ou[4]);
            }
        }
        grid.sync();

        // ---- gru: grid-stride over 1264 tiles ----
        const unsigned short* Wc = wc5 + (size_t)l * 2 * 768 * 256;
        for (int tile = bid; tile < 1264; tile += nblk) {
            int ww = (tile & 7) * 158 + (tile >> 3);
            const int mt = ww >> 3, dgp = ww & 7;
            const int m0 = mt * 128;

            f32x4 aR[2], aZ[2], aI[2], aH[2];
            const f32x4 z4 = {0.f, 0.f, 0.f, 0.f};
#pragma unroll
            for (int i = 0; i < 2; ++i) { aR[i] = z4; aZ[i] = z4; aI[i] = z4; aH[i] = z4; }

            auto do_half = [&](const unsigned short* __restrict__ aptr,
                               const unsigned short* __restrict__ wcb,
                               f32x4 (&aX)[2]) {
                for (int kq = 0; kq < 4; ++kq) {
                    const int ka = kq * 64;
#pragma unroll
                    for (int rnd = 0; rnd < 2; ++rnd) {
                        int cb = rnd * 512 + (w << 6);
                        int c = cb + lane;
                        int row = c >> 3, sl = c & 7;
                        int gsl = sl ^ (row & 7);
                        gload16(aptr + (size_t)(m0 + row) * 256 + ka + gsl * 8, &As[cb * 8]);
                    }
                    {
                        int cb = (w << 6);
                        int c = cb + lane;
                        int row = c >> 3, sl = c & 7;
                        int gsl = sl ^ (row & 7);
                        gload16(wcb + (size_t)(dgp * 96 + row) * 256 + ka + gsl * 8, &Bs[cb * 8]);
                    }
                    if (w < 4) {
                        int cb = 512 + (w << 6);
                        int c = cb + lane;
                        int row = c >> 3, sl = c & 7;
                        int gsl = sl ^ (row & 7);
                        gload16(wcb + (size_t)(dgp * 96 + row) * 256 + ka + gsl * 8, &Bs[cb * 8]);
                    }
                    __syncthreads();
#pragma unroll
                    for (int ks = 0; ks < 2; ++ks) {
                        const int slot = ks * 4 + (lane >> 4);
                        bf16x8 a[2], bfr[3];
#pragma unroll
                        for (int mi = 0; mi < 2; ++mi) {
                            int row = wm * 32 + mi * 16 + (lane & 15);
                            a[mi] = *reinterpret_cast<const bf16x8*>(&As[row * 64 + ((slot ^ (row & 7)) << 3)]);
                        }
#pragma unroll
                        for (int g3 = 0; g3 < 3; ++g3) {
                            int row = wn * 48 + g3 * 16 + (lane & 15);
                            bfr[g3] = *reinterpret_cast<const bf16x8*>(&Bs[row * 64 + ((slot ^ (row & 7)) << 3)]);
                        }
#pragma unroll
                        for (int mi = 0; mi < 2; ++mi) {
                            aR[mi] = __builtin_amdgcn_mfma_f32_16x16x32_bf16(a[mi], bfr[0], aR[mi], 0, 0, 0);
                            aZ[mi] = __builtin_amdgcn_mfma_f32_16x16x32_bf16(a[mi], bfr[1], aZ[mi], 0, 0, 0);
                            aX[mi] = __builtin_amdgcn_mfma_f32_16x16x32_bf16(a[mi], bfr[2], aX[mi], 0, 0, 0);
                        }
                    }
                    __syncthreads();
                }
            };

            do_half(aggbf, Wc, aI);
            do_half(hcur, Wc + 768 * 256, aH);

            const int d = (dgp * 2 + wn) * 16 + (lane & 15);
            const float bir = b_ih[d],        bhr = b_hh[d];
            const float biz = b_ih[256 + d],  bhz = b_hh[256 + d];
            const float bin_ = b_ih[512 + d], bhn = b_hh[512 + d];
#pragma unroll
            for (int mi = 0; mi < 2; ++mi)
#pragma unroll
                for (int r = 0; r < 4; ++r) {
                    int grow = m0 + wm * 32 + mi * 16 + (lane >> 4) * 4 + r;
                    if (grow >= NN) continue;
                    size_t idx = (size_t)grow * 256 + d;
                    float rr = fast_sigmoid(aR[mi][r] + bir + bhr);
                    float zz = fast_sigmoid(aZ[mi][r] + biz + bhz);
                    float nn = fast_tanh(aI[mi][r] + bin_ + rr * (aH[mi][r] + bhn));
                    float hp = first ? x_f32[idx] : bf2f(hcur[idx]);
                    float hv = (1.f - zz) * nn + zz * hp;
                    if (last) h_out[idx] = hv;
                    hnxt[idx] = f2bf(hv);
                }
        }
        grid.sync();
    }
}

// ---------------- launch ----------------

extern "C" void kernel_launch(void* const* d_in, const int* in_sizes, int n_in,
                              void* d_out, int out_size, void* d_ws, size_t ws_size,
                              hipStream_t stream) {
    const float* x     = (const float*)d_in[0];
    const int*   eidx  = (const int*)d_in[1];
    const float* eattr = (const float*)d_in[2];
    const float* W     = (const float*)d_in[3];
    const float* wih   = (const float*)d_in[4];
    const float* whh   = (const float*)d_in[5];
    const float* bih   = (const float*)d_in[6];
    const float* bhh   = (const float*)d_in[7];
    float* out = (float*)d_out;
    const int* esrc = eidx;
    const int* edst = eidx + NE;

    char* p = (char*)d_ws;
    auto alloc = [&](size_t bytes) -> char* {
        char* r = p; p += (bytes + 255) & ~(size_t)255; return r;
    };
    unsigned short* hbfA  = (unsigned short*)alloc((size_t)NN * DD * 2);
    unsigned short* hbfB  = (unsigned short*)alloc((size_t)NN * DD * 2);
    unsigned short* aggbf = (unsigned short*)alloc((size_t)NN * DD * 2);
    unsigned short* wnb   = (unsigned short*)alloc((size_t)5 * DD * DD * 2);
    unsigned short* wihb  = (unsigned short*)alloc((size_t)768 * DD * 2);
    unsigned short* wc5   = (unsigned short*)alloc((size_t)5 * 2 * 768 * 256 * 2);
    int*   deg    = (int*)alloc((size_t)NN * 4);
    int*   basep  = (int*)alloc((size_t)(NN + 1) * 4);
    int*   ssrc   = (int*)alloc((size_t)NE * 4);
    float* sattr  = (float*)alloc((size_t)NE * 4);
    alloc(262144);  // guard slack: padded tile rows (20000..20223) read in-workspace garbage

    hipMemsetAsync(deg, 0, (size_t)NN * 4, stream);
    prep_kernel<<<6954, 256, 0, stream>>>(x, hbfA, W, wnb, wih, wihb, whh, wc5, edst, deg);
    pgemm_kernel<<<dim3(12, 10), 256, 0, stream>>>(wnb, wihb, wc5);
    scan_kernel<<<1, 1024, 0, stream>>>(deg, basep);
    fill_kernel<<<1250, 256, 0, stream>>>(esrc, edst, eattr, basep, ssrc, sattr);

    // ---- cooperative path if the runtime confirms >=4 blocks/CU co-residency ----
    bool coop_done = false;
    int coop_attr = 0;
    if (hipDeviceGetAttribute(&coop_attr, hipDeviceAttributeCooperativeLaunch, 0) == hipSuccess
        && coop_attr) {
        int maxb = 0;
        if (hipOccupancyMaxActiveBlocksPerMultiprocessor(&maxb, mega_kernel, 512, 0) == hipSuccess
            && maxb >= 4) {
            hipDeviceProp_t prop;
            if (hipGetDeviceProperties(&prop, 0) == hipSuccess) {
                int grid = maxb * prop.multiProcessorCount;
                if (grid > 1264) grid = 1264;
                void* kargs[] = {
                    (void*)&hbfA, (void*)&hbfB, (void*)&aggbf, (void*)&wc5,
                    (void*)&basep, (void*)&deg, (void*)&ssrc, (void*)&sattr,
                    (void*)&bih, (void*)&bhh, (void*)&x, (void*)&out
                };
                hipError_t e = hipLaunchCooperativeKernel((const void*)mega_kernel,
                                                          dim3(grid), dim3(512),
                                                          kargs, 0, stream);
                coop_done = (e == hipSuccess);
            }
        }
    }

    if (!coop_done) {
        // fallback: R13's proven 10-dispatch layer loop
        unsigned short* hb_cur = hbfA;
        unsigned short* hb_nxt = hbfB;
        for (int l = 0; l < 5; ++l) {
            gather_agg_kernel<<<5000, 256, 0, stream>>>(hb_cur, basep, deg, ssrc, sattr, aggbf);
            gru4_kernel<<<1264, 512, 0, stream>>>(aggbf, hb_cur, wc5 + (size_t)l * 2 * 768 * 256,
                                                  bih, bhh, x, out, hb_nxt,
                                                  (l == 0) ? 1 : 0, (l == 4) ? 1 : 0);
            unsigned short* tmp = hb_cur; hb_cur = hb_nxt; hb_nxt = tmp;
        }
    }
    (void)in_sizes; (void)n_in; (void)out_size; (void)ws_size;
}